// Round 1
// 432.377 us; speedup vs baseline: 1.1431x; 1.1431x over previous
//
#include <hip/hip_runtime.h>

// Problem constants (fixed by the reference)
#define Bb  2
#define Ss  2048
#define Dd  2048
#define HKV 8
#define QPK 4
#define HD  64
#define MR  (Bb * Ss)   // 4096 token rows
#define NQ  2048        // HQ*HD
#define NKV 512         // HKV*HD

#define LOG2E 1.4426950408889634f

typedef unsigned short u16;
typedef __attribute__((ext_vector_type(8))) short s16x8;   // 8 x bf16 (4 VGPRs)
typedef __attribute__((ext_vector_type(4))) float f32x4;   // MFMA accumulator

__device__ __forceinline__ u16 f2bf(float f) {
  unsigned u = __float_as_uint(f);
  u += 0x7fffu + ((u >> 16) & 1u);   // RNE; inputs finite
  return (u16)(u >> 16);
}

// async global->LDS, 16B per lane; LDS dest is wave-uniform base + lane*16
__device__ __forceinline__ void gload16(const u16* g, u16* l) {
  __builtin_amdgcn_global_load_lds(
      (const __attribute__((address_space(1))) unsigned int*)g,
      (__attribute__((address_space(3))) unsigned int*)l, 16, 0, 0);
}

// ---------------------------------------------------------------------------
// LayerNorm: one block per row, fp32 in -> bf16 out
// ---------------------------------------------------------------------------
__global__ __launch_bounds__(256) void ln_kernel(
    const float* __restrict__ x, const float* __restrict__ g,
    const float* __restrict__ be, u16* __restrict__ xn)
{
  int row = blockIdx.x;
  int tid = threadIdx.x;
  const float4* xr = (const float4*)(x + (size_t)row * Dd);
  float4 a = xr[tid];
  float4 b4 = xr[tid + 256];
  float s  = a.x + a.y + a.z + a.w + b4.x + b4.y + b4.z + b4.w;
  float ss = a.x*a.x + a.y*a.y + a.z*a.z + a.w*a.w
           + b4.x*b4.x + b4.y*b4.y + b4.z*b4.z + b4.w*b4.w;
  #pragma unroll
  for (int off = 32; off > 0; off >>= 1) {
    s  += __shfl_down(s, off);
    ss += __shfl_down(ss, off);
  }
  __shared__ float red[8];
  int lane = tid & 63, w = tid >> 6;
  if (lane == 0) { red[w] = s; red[4 + w] = ss; }
  __syncthreads();
  s  = red[0] + red[1] + red[2] + red[3];
  ss = red[4] + red[5] + red[6] + red[7];
  float mu = s * (1.0f / Dd);
  float rs = rsqrtf(ss * (1.0f / Dd) - mu * mu + 1e-5f);

  u16* xo = xn + (size_t)row * Dd;
  const float4* gv4 = (const float4*)g;
  const float4* bv4 = (const float4*)be;
  #pragma unroll
  for (int p = 0; p < 2; ++p) {
    int idx = tid + p * 256;
    float4 xv = (p == 0) ? a : b4;
    float4 gg = gv4[idx], bb = bv4[idx];
    ushort4 pk;
    pk.x = f2bf((xv.x - mu) * rs * gg.x + bb.x);
    pk.y = f2bf((xv.y - mu) * rs * gg.y + bb.y);
    pk.z = f2bf((xv.z - mu) * rs * gg.z + bb.z);
    pk.w = f2bf((xv.w - mu) * rs * gg.w + bb.w);
    *(ushort4*)(xo + idx * 4) = pk;
  }
}

// ---------------------------------------------------------------------------
// Weight transpose + cast: W (K x N) fp32 -> WT (N x K) bf16
// ---------------------------------------------------------------------------
__global__ __launch_bounds__(256) void transpose_cast(
    const float* __restrict__ W, u16* __restrict__ WT, int K, int N)
{
  __shared__ float tile[32][33];
  int tx = threadIdx.x & 31, ty = threadIdx.x >> 5;  // ty 0..7
  int n0 = blockIdx.x * 32, k0 = blockIdx.y * 32;
  #pragma unroll
  for (int i = 0; i < 4; ++i)
    tile[ty + 8 * i][tx] = W[(size_t)(k0 + ty + 8 * i) * N + n0 + tx];
  __syncthreads();
  #pragma unroll
  for (int i = 0; i < 4; ++i)
    WT[(size_t)(n0 + ty + 8 * i) * K + k0 + tx] = f2bf(tile[tx][ty + 8 * i]);
}

// ---------------------------------------------------------------------------
// V transpose: vb (b,t, h*64+d) bf16 -> vT (b*512 + h*64+d, t) bf16
// ---------------------------------------------------------------------------
__global__ __launch_bounds__(256) void transpose_v(
    const u16* __restrict__ vb, u16* __restrict__ vT)
{
  __shared__ u16 tile[32][33];
  int tx = threadIdx.x & 31, ty = threadIdx.x >> 5;
  int c0 = blockIdx.x * 32;     // 0..511  (h*64+d)
  int r0 = blockIdx.y * 32;     // 0..4095 (b*2048+t), tiles never cross b
  #pragma unroll
  for (int i = 0; i < 4; ++i)
    tile[ty + 8 * i][tx] = vb[(size_t)(r0 + ty + 8 * i) * NKV + c0 + tx];
  __syncthreads();
  int b = r0 >> 11, t = r0 & 2047;
  #pragma unroll
  for (int i = 0; i < 4; ++i)
    vT[((size_t)(b * NKV + c0 + ty + 8 * i)) * Ss + t + tx] = tile[tx][ty + 8 * i];
}

// ---------------------------------------------------------------------------
// m97-structure GEMM core: 128x128 tile, BK=64, global_load_lds width-16
// staging into LINEAR LDS [128][64], 2 barriers per K-step.
// C layout per wave: wm=(wave>>1)*64, wn=(wave&1)*64; acc[i][j][r] holds
// row = wm+i*16+quad*4+r, col = wn+j*16+m16.
// ---------------------------------------------------------------------------
__device__ __forceinline__ void gemm_core128(
    const u16* __restrict__ A, const u16* __restrict__ BT, int K,
    int brow128, int bcol128, u16* __restrict__ As, u16* __restrict__ Bs,
    f32x4 (&acc)[4][4])
{
  int tid  = threadIdx.x;
  int lane = tid & 63, wave = tid >> 6;
  int wm = (wave >> 1) * 64, wn = (wave & 1) * 64;
  int m16 = lane & 15, quad = lane >> 4;
  // staging: wave w owns rows [32w, 32w+32) of both tiles; 4 chunks of 8 rows,
  // each chunk = one global_load_lds_dwordx4 (64 lanes x 16B = 8 rows x 128B)
  int srow = lane >> 3;            // 0..7 within chunk
  int scol = (lane & 7) * 8;       // element col offset (16B granules)
  const u16* Ag = A  + (size_t)(brow128 + wave * 32 + srow) * K + scol;
  const u16* Bg = BT + (size_t)(bcol128 + wave * 32 + srow) * K + scol;
  u16* Asw = As + (size_t)(wave * 32) * 64;
  u16* Bsw = Bs + (size_t)(wave * 32) * 64;

  for (int k0 = 0; k0 < K; k0 += 64) {
    __syncthreads();   // all waves done reading previous tile
    #pragma unroll
    for (int i = 0; i < 4; ++i) {
      gload16(Ag + (size_t)(i * 8) * K + k0, Asw + i * 512);
      gload16(Bg + (size_t)(i * 8) * K + k0, Bsw + i * 512);
    }
    __syncthreads();   // compiler drains vmcnt(0) before barrier -> tile ready
    s16x8 af[4][2], bf[4][2];
    #pragma unroll
    for (int i = 0; i < 4; ++i) {
      af[i][0] = *(const s16x8*)&As[(size_t)(wm + i * 16 + m16) * 64 + quad * 8];
      af[i][1] = *(const s16x8*)&As[(size_t)(wm + i * 16 + m16) * 64 + 32 + quad * 8];
      bf[i][0] = *(const s16x8*)&Bs[(size_t)(wn + i * 16 + m16) * 64 + quad * 8];
      bf[i][1] = *(const s16x8*)&Bs[(size_t)(wn + i * 16 + m16) * 64 + 32 + quad * 8];
    }
    #pragma unroll
    for (int i = 0; i < 4; ++i)
      #pragma unroll
      for (int j = 0; j < 4; ++j) {
        acc[i][j] = __builtin_amdgcn_mfma_f32_16x16x32_bf16(af[i][0], bf[j][0], acc[i][j], 0, 0, 0);
        acc[i][j] = __builtin_amdgcn_mfma_f32_16x16x32_bf16(af[i][1], bf[j][1], acc[i][j], 0, 0, 0);
      }
  }
}

// Generic C = (A @ BT^T + bias) * scale, fp32 or bf16 out
template<bool BF16OUT>
__global__ __launch_bounds__(256) void gemm_bt2(
    const u16* __restrict__ A, const u16* __restrict__ BT,
    const float* __restrict__ bias, void* __restrict__ Cv,
    int N, int K, float scale)
{
  __shared__ u16 As[128 * 64];
  __shared__ u16 Bs[128 * 64];
  f32x4 acc[4][4] = {};
  gemm_core128(A, BT, K, blockIdx.y * 128, blockIdx.x * 128, As, Bs, acc);

  int lane = threadIdx.x & 63, wave = threadIdx.x >> 6;
  int wm = (wave >> 1) * 64, wn = (wave & 1) * 64;
  int m16 = lane & 15, quad = lane >> 4;
  #pragma unroll
  for (int i = 0; i < 4; ++i) {
    #pragma unroll
    for (int j = 0; j < 4; ++j) {
      int col = blockIdx.x * 128 + wn + j * 16 + m16;
      float bcol = bias[col];
      #pragma unroll
      for (int r = 0; r < 4; ++r) {
        int rowg = blockIdx.y * 128 + wm + i * 16 + quad * 4 + r;
        float val = (acc[i][j][r] + bcol) * scale;
        if constexpr (BF16OUT)
          ((u16*)Cv)[(size_t)rowg * N + col] = f2bf(val);
        else
          ((float*)Cv)[(size_t)rowg * N + col] = val;
      }
    }
  }
}

// Fused QKV projection: BT = concat rows [WqT(2048) ; WkT(512) ; WvT(512)],
// N = 3072 -> grid 24 x 32 = 768 blocks (full GPU vs 128-block K/V gemms).
// Tile (128 cols) never straddles a region boundary.
__global__ __launch_bounds__(256) void gemm_qkv(
    const u16* __restrict__ A, const u16* __restrict__ BT,
    const float* __restrict__ bq, const float* __restrict__ bk,
    const float* __restrict__ bv,
    u16* __restrict__ qb, u16* __restrict__ kb, u16* __restrict__ vb)
{
  __shared__ u16 As[128 * 64];
  __shared__ u16 Bs[128 * 64];
  f32x4 acc[4][4] = {};
  gemm_core128(A, BT, Dd, blockIdx.y * 128, blockIdx.x * 128, As, Bs, acc);

  u16* outp; const float* bp; int ldo, colbase; float scale;
  if (blockIdx.x < 16)      { outp = qb; bp = bq; ldo = NQ;  colbase = blockIdx.x * 128;        scale = 0.125f * LOG2E; }
  else if (blockIdx.x < 20) { outp = kb; bp = bk; ldo = NKV; colbase = (blockIdx.x - 16) * 128; scale = 1.0f; }
  else                      { outp = vb; bp = bv; ldo = NKV; colbase = (blockIdx.x - 20) * 128; scale = 1.0f; }

  int lane = threadIdx.x & 63, wave = threadIdx.x >> 6;
  int wm = (wave >> 1) * 64, wn = (wave & 1) * 64;
  int m16 = lane & 15, quad = lane >> 4;
  #pragma unroll
  for (int i = 0; i < 4; ++i) {
    #pragma unroll
    for (int j = 0; j < 4; ++j) {
      int col = colbase + wn + j * 16 + m16;
      float bcol = bp[col];
      #pragma unroll
      for (int r = 0; r < 4; ++r) {
        int rowg = blockIdx.y * 128 + wm + i * 16 + quad * 4 + r;
        outp[(size_t)rowg * ldo + col] = f2bf((acc[i][j][r] + bcol) * scale);
      }
    }
  }
}

// ---------------------------------------------------------------------------
// Pass A: per-column softmax stats over the QUERY axis (base-2 domain).
// ---------------------------------------------------------------------------
__global__ __launch_bounds__(256) void pass_a_mfma(
    const u16* __restrict__ qb, const u16* __restrict__ kb,
    float* __restrict__ cst)
{
  __shared__ u16 Qs[64][70];   // stride 35 dwords: bank = 3*m16+4*quad, depth<=2
  int combo = blockIdx.x;
  int qk = combo & 3, bh = combo >> 2;
  int b = bh >> 3, h = bh & 7;
  int g = blockIdx.y;                     // 0..15, longest first
  int tid = threadIdx.x;
  int lane = tid & 63, wave = tid >> 6;
  int m16 = lane & 15, quad = lane >> 4;
  int T0w = g * 128 + wave * 32;          // wave's 32 T-columns

  const u16* kbase = kb + (size_t)b * Ss * NKV + h * HD;
  const u16* qbase = qb + (size_t)b * Ss * NQ + (h * QPK + qk) * HD;

  s16x8 kf[2][2];   // B-operand frags (n=T), loaded once
  #pragma unroll
  for (int jg = 0; jg < 2; ++jg)
    #pragma unroll
    for (int kh = 0; kh < 2; ++kh)
      kf[jg][kh] = *(const s16x8*)(kbase + (size_t)(T0w + jg * 16 + m16) * NKV + kh * 32 + quad * 8);

  float ms[2] = {-1e30f, -1e30f};
  float ls[2] = {0.f, 0.f};
  int sr = tid >> 3, sc = (tid & 7) * 8;
  int tDiag = T0w & ~63;

  for (int t0 = g * 128; t0 < Ss; t0 += 64) {
    __syncthreads();
    *(int4*)&Qs[sr][sc]      = *(const int4*)(qbase + (size_t)(t0 + sr) * NQ + sc);
    *(int4*)&Qs[sr + 32][sc] = *(const int4*)(qbase + (size_t)(t0 + sr + 32) * NQ + sc);
    __syncthreads();
    if (t0 + 63 < T0w) continue;   // wave not yet active (barriers already done)

    s16x8 af[4][2];
    #pragma unroll
    for (int i = 0; i < 4; ++i) {
      af[i][0] = *(const s16x8*)&Qs[i * 16 + m16][quad * 8];
      af[i][1] = *(const s16x8*)&Qs[i * 16 + m16][32 + quad * 8];
    }
    f32x4 acc[4][2];
    #pragma unroll
    for (int i = 0; i < 4; ++i)
      #pragma unroll
      for (int jg = 0; jg < 2; ++jg) {
        f32x4 z = {};
        z = __builtin_amdgcn_mfma_f32_16x16x32_bf16(af[i][0], kf[jg][0], z, 0, 0, 0);
        acc[i][jg] = __builtin_amdgcn_mfma_f32_16x16x32_bf16(af[i][1], kf[jg][1], z, 0, 0, 0);
      }
    if (t0 == tDiag) {   // diagonal block: mask t < T with very-low sentinel
      #pragma unroll
      for (int i = 0; i < 4; ++i)
        #pragma unroll
        for (int jg = 0; jg < 2; ++jg) {
          int tg = t0 + i * 16 + quad * 4;
          int Tg = T0w + jg * 16 + m16;
          #pragma unroll
          for (int r = 0; r < 4; ++r)
            if (tg + r < Tg) acc[i][jg][r] = -3e38f;
        }
    }
    #pragma unroll
    for (int jg = 0; jg < 2; ++jg) {
      float bm = -3e38f;
      #pragma unroll
      for (int i = 0; i < 4; ++i)
        #pragma unroll
        for (int r = 0; r < 4; ++r) bm = fmaxf(bm, acc[i][jg][r]);
      float mn = fmaxf(ms[jg], bm);
      float se = 0.f;
      #pragma unroll
      for (int i = 0; i < 4; ++i)
        #pragma unroll
        for (int r = 0; r < 4; ++r) se += exp2f(acc[i][jg][r] - mn);
      ls[jg] = ls[jg] * exp2f(ms[jg] - mn) + se;
      ms[jg] = mn;
    }
  }
  // cross-quad merge (cols live on m16; quads hold disjoint t-subsets)
  #pragma unroll
  for (int jg = 0; jg < 2; ++jg) {
    float m = ms[jg], l = ls[jg];
    #pragma unroll
    for (int off = 16; off <= 32; off <<= 1) {
      float mo = __shfl_xor(m, off);
      float lo = __shfl_xor(l, off);
      float mn = fmaxf(m, mo);
      l = l * exp2f(m - mn) + lo * exp2f(mo - mn);
      m = mn;
    }
    if (quad == 0)
      cst[(size_t)(bh * QPK + qk) * Ss + T0w + jg * 16 + m16] = m + __log2f(l);
  }
}

// ---------------------------------------------------------------------------
// Pass B: out[t,:] = sum_{T<=t} exp2(s2(t,T)-c[T]) * v[T,:]
// ---------------------------------------------------------------------------
__global__ __launch_bounds__(256) void pass_b_mfma(
    const u16* __restrict__ qb, const u16* __restrict__ kb,
    const u16* __restrict__ vT, const float* __restrict__ cst,
    u16* __restrict__ attn)
{
  __shared__ u16 Ks[64][70];
  __shared__ u16 Vs[64][70];
  __shared__ u16 P[4][16][70];
  int combo = blockIdx.x;
  int qk = combo & 3, bh = combo >> 2;
  int b = bh >> 3, h = bh & 7;
  int g = 31 - blockIdx.y;                // longest first
  int tid = threadIdx.x;
  int lane = tid & 63, wave = tid >> 6;
  int m16 = lane & 15, quad = lane >> 4;
  int trow = g * 64 + wave * 16;          // wave's 16 t-rows

  const u16* qbase = qb + (size_t)b * Ss * NQ + (h * QPK + qk) * HD;
  const u16* kbase = kb + (size_t)b * Ss * NKV + h * HD;
  const u16* vbase = vT + (size_t)(bh * 64) * Ss;
  const float* cbase = cst + (size_t)(bh * QPK + qk) * Ss;

  s16x8 qf[2];   // B-operand (n=t) frags for this wave's rows
  #pragma unroll
  for (int kh = 0; kh < 2; ++kh)
    qf[kh] = *(const s16x8*)(qbase + (size_t)(trow + m16) * NQ + kh * 32 + quad * 8);

  f32x4 oacc[4] = {};   // C-layout: row t = quad*4+r, col d = dj*16+m16
  int sr = tid >> 3, sc = (tid & 7) * 8;
  int Tend = g * 64;

  for (int T0 = 0; T0 <= Tend; T0 += 64) {
    __syncthreads();
    *(int4*)&Ks[sr][sc]      = *(const int4*)(kbase + (size_t)(T0 + sr) * NKV + sc);
    *(int4*)&Ks[sr + 32][sc] = *(const int4*)(kbase + (size_t)(T0 + sr + 32) * NKV + sc);
    *(int4*)&Vs[sr][sc]      = *(const int4*)(vbase + (size_t)sr * Ss + T0 + sc);
    *(int4*)&Vs[sr + 32][sc] = *(const int4*)(vbase + (size_t)(sr + 32) * Ss + T0 + sc);
    __syncthreads();
    bool diag = (T0 == Tend);
    // ---- scores S^T (m=T, n=t) -> normalized P (bf16) in LDS ----
    #pragma unroll
    for (int i = 0; i < 4; ++i) {
      s16x8 k0 = *(const s16x8*)&Ks[i * 16 + m16][quad * 8];
      s16x8 k1 = *(const s16x8*)&Ks[i * 16 + m16][32 + quad * 8];
      f32x4 z = {};
      z = __builtin_amdgcn_mfma_f32_16x16x32_bf16(k0, qf[0], z, 0, 0, 0);
      z = __builtin_amdgcn_mfma_f32_16x16x32_bf16(k1, qf[1], z, 0, 0, 0);
      float4 cc = *(const float4*)(cbase + T0 + i * 16 + quad * 4);
      float w0 = exp2f(z[0] - cc.x);
      float w1 = exp2f(z[1] - cc.y);
      float w2 = exp2f(z[2] - cc.z);
      float w3 = exp2f(z[3] - cc.w);
      if (diag) {
        int t  = trow + m16;
        int Tg = T0 + i * 16 + quad * 4;
        if (Tg + 0 > t) w0 = 0.f;
        if (Tg + 1 > t) w1 = 0.f;
        if (Tg + 2 > t) w2 = 0.f;
        if (Tg + 3 > t) w3 = 0.f;
      }
      unsigned u0 = __float_as_uint(w0) + 0x8000u;
      unsigned u1 = __float_as_uint(w1) + 0x8000u;
      unsigned u2 = __float_as_uint(w2) + 0x8000u;
      unsigned u3 = __float_as_uint(w3) + 0x8000u;
      uint2 pk;
      pk.x = (u0 >> 16) | (u1 & 0xffff0000u);
      pk.y = (u2 >> 16) | (u3 & 0xffff0000u);
      *(uint2*)&P[wave][m16][i * 16 + quad * 4] = pk;
    }
    // ---- PV: oacc += P(t,T) @ V(T,d)^T ----
    #pragma unroll
    for (int kh = 0; kh < 2; ++kh) {
      s16x8 pa = *(const s16x8*)&P[wave][m16][kh * 32 + quad * 8];
      #pragma unroll
      for (int dj = 0; dj < 4; ++dj) {
        s16x8 vf = *(const s16x8*)&Vs[dj * 16 + m16][kh * 32 + quad * 8];
        oacc[dj] = __builtin_amdgcn_mfma_f32_16x16x32_bf16(pa, vf, oacc[dj], 0, 0, 0);
      }
    }
  }
  // ---- epilogue: attn (b, t, (h*QPK+qk)*64 + d) bf16 ----
  u16* abase = attn + (size_t)b * Ss * NQ + (h * QPK + qk) * HD;
  #pragma unroll
  for (int dj = 0; dj < 4; ++dj)
    #pragma unroll
    for (int r = 0; r < 4; ++r)
      abase[(size_t)(trow + quad * 4 + r) * NQ + dj * 16 + m16] = f2bf(oacc[dj][r]);
}

// ---------------------------------------------------------------------------
extern "C" void kernel_launch(void* const* d_in, const int* in_sizes, int n_in,
                              void* d_out, int out_size, void* d_ws, size_t ws_size,
                              hipStream_t stream)
{
  (void)in_sizes; (void)n_in; (void)out_size; (void)ws_size;
  const float* x   = (const float*)d_in[0];
  const float* lng = (const float*)d_in[1];
  const float* lnb = (const float*)d_in[2];
  const float* Wq  = (const float*)d_in[3];
  const float* bq  = (const float*)d_in[4];
  const float* Wk  = (const float*)d_in[5];
  const float* bk  = (const float*)d_in[6];
  const float* Wv  = (const float*)d_in[7];
  const float* bv  = (const float*)d_in[8];
  const float* Wo  = (const float*)d_in[9];
  const float* bo  = (const float*)d_in[10];
  float* out = (float*)d_out;

  char* ws = (char*)d_ws;
  size_t off = 0;
  auto take = [&](size_t bytes) -> char* {
    char* p = ws + off;
    off += (bytes + 255) & ~(size_t)255;
    return p;
  };
  u16*    xnb   = (u16*)take((size_t)MR * Dd * 2);             // 16 MB
  u16*    wqkvT = (u16*)take((size_t)(NQ + 2 * NKV) * Dd * 2); // 12 MB (Q;K;V rows)
  u16*    woT   = (u16*)take((size_t)Dd * NQ * 2);             // 8 MB
  u16*    qbB   = (u16*)take((size_t)MR * NQ * 2);             // 16 MB
  u16*    kbB   = (u16*)take((size_t)MR * NKV * 2);            // 4 MB
  u16*    vbB   = (u16*)take((size_t)MR * NKV * 2);            // 4 MB
  u16*    vTb   = (u16*)take((size_t)MR * NKV * 2);            // 4 MB
  float*  cst   = (float*)take((size_t)Bb * HKV * QPK * Ss * 4); // 0.5 MB
  u16*    attnb = (u16*)take((size_t)MR * NQ * 2);             // 16 MB

  ln_kernel<<<MR, 256, 0, stream>>>(x, lng, lnb, xnb);
  // concatenated BT: rows [0,2048)=WqT, [2048,2560)=WkT, [2560,3072)=WvT
  transpose_cast<<<dim3(NQ / 32, Dd / 32), 256, 0, stream>>>(Wq, wqkvT, Dd, NQ);
  transpose_cast<<<dim3(NKV / 32, Dd / 32), 256, 0, stream>>>(Wk, wqkvT + (size_t)NQ * Dd, Dd, NKV);
  transpose_cast<<<dim3(NKV / 32, Dd / 32), 256, 0, stream>>>(Wv, wqkvT + (size_t)(NQ + NKV) * Dd, Dd, NKV);
  transpose_cast<<<dim3(NQ / 32, Dd / 32), 256, 0, stream>>>(Wo, woT, Dd, NQ);

  // fused Q/K/V projection (q pre-scaled by 1/sqrt(HD) * log2(e))
  gemm_qkv<<<dim3((NQ + 2 * NKV) / 128, MR / 128), 256, 0, stream>>>(
      xnb, wqkvT, bq, bk, bv, qbB, kbB, vbB);
  transpose_v<<<dim3(NKV / 32, MR / 32), 256, 0, stream>>>(vbB, vTb);

  pass_a_mfma<<<dim3(64, 16), 256, 0, stream>>>(qbB, kbB, cst);
  pass_b_mfma<<<dim3(64, 32), 256, 0, stream>>>(qbB, kbB, vTb, cst, attnb);

  gemm_bt2<false><<<dim3(Dd / 128, MR / 128), 256, 0, stream>>>(
      attnb, woT, bo, out, Dd, NQ, 1.0f);
}

// Round 2
// 397.804 us; speedup vs baseline: 1.2424x; 1.0869x over previous
//
#include <hip/hip_runtime.h>

// Problem constants (fixed by the reference)
#define Bb  2
#define Ss  2048
#define Dd  2048
#define HKV 8
#define QPK 4
#define HD  64
#define MR  (Bb * Ss)   // 4096 token rows
#define NQ  2048        // HQ*HD
#define NKV 512         // HKV*HD

#define LOG2E 1.4426950408889634f

typedef unsigned short u16;
typedef unsigned int u32;
typedef __attribute__((ext_vector_type(8))) short s16x8;   // 8 x bf16 (4 VGPRs)
typedef __attribute__((ext_vector_type(4))) float f32x4;   // MFMA accumulator

__device__ __forceinline__ u16 f2bf(float f) {
  unsigned u = __float_as_uint(f);
  u += 0x7fffu + ((u >> 16) & 1u);   // RNE; inputs finite
  return (u16)(u >> 16);
}

// async global->LDS, 16B per lane; LDS dest is wave-uniform base + lane*16
__device__ __forceinline__ void gload16(const u16* g, u16* l) {
  __builtin_amdgcn_global_load_lds(
      (const __attribute__((address_space(1))) unsigned int*)g,
      (__attribute__((address_space(3))) unsigned int*)l, 16, 0, 0);
}

// pack two f32 -> one dword of 2 bf16 (lo = a, hi = b)
__device__ __forceinline__ u32 cvtpk_bf16(float a, float b) {
  u32 r;
  asm volatile("v_cvt_pk_bf16_f32 %0, %1, %2" : "=v"(r) : "v"(a), "v"(b));
  return r;
}

// ---------------------------------------------------------------------------
// LayerNorm: one block per row, fp32 in -> bf16 out
// ---------------------------------------------------------------------------
__global__ __launch_bounds__(256) void ln_kernel(
    const float* __restrict__ x, const float* __restrict__ g,
    const float* __restrict__ be, u16* __restrict__ xn)
{
  int row = blockIdx.x;
  int tid = threadIdx.x;
  const float4* xr = (const float4*)(x + (size_t)row * Dd);
  float4 a = xr[tid];
  float4 b4 = xr[tid + 256];
  float s  = a.x + a.y + a.z + a.w + b4.x + b4.y + b4.z + b4.w;
  float ss = a.x*a.x + a.y*a.y + a.z*a.z + a.w*a.w
           + b4.x*b4.x + b4.y*b4.y + b4.z*b4.z + b4.w*b4.w;
  #pragma unroll
  for (int off = 32; off > 0; off >>= 1) {
    s  += __shfl_down(s, off);
    ss += __shfl_down(ss, off);
  }
  __shared__ float red[8];
  int lane = tid & 63, w = tid >> 6;
  if (lane == 0) { red[w] = s; red[4 + w] = ss; }
  __syncthreads();
  s  = red[0] + red[1] + red[2] + red[3];
  ss = red[4] + red[5] + red[6] + red[7];
  float mu = s * (1.0f / Dd);
  float rs = rsqrtf(ss * (1.0f / Dd) - mu * mu + 1e-5f);

  u16* xo = xn + (size_t)row * Dd;
  const float4* gv4 = (const float4*)g;
  const float4* bv4 = (const float4*)be;
  #pragma unroll
  for (int p = 0; p < 2; ++p) {
    int idx = tid + p * 256;
    float4 xv = (p == 0) ? a : b4;
    float4 gg = gv4[idx], bb = bv4[idx];
    ushort4 pk;
    pk.x = f2bf((xv.x - mu) * rs * gg.x + bb.x);
    pk.y = f2bf((xv.y - mu) * rs * gg.y + bb.y);
    pk.z = f2bf((xv.z - mu) * rs * gg.z + bb.z);
    pk.w = f2bf((xv.w - mu) * rs * gg.w + bb.w);
    *(ushort4*)(xo + idx * 4) = pk;
  }
}

// ---------------------------------------------------------------------------
// Weight transpose + cast: W (K x N) fp32 -> WT (N x K) bf16
// ---------------------------------------------------------------------------
__global__ __launch_bounds__(256) void transpose_cast(
    const float* __restrict__ W, u16* __restrict__ WT, int K, int N)
{
  __shared__ float tile[32][33];
  int tx = threadIdx.x & 31, ty = threadIdx.x >> 5;  // ty 0..7
  int n0 = blockIdx.x * 32, k0 = blockIdx.y * 32;
  #pragma unroll
  for (int i = 0; i < 4; ++i)
    tile[ty + 8 * i][tx] = W[(size_t)(k0 + ty + 8 * i) * N + n0 + tx];
  __syncthreads();
  #pragma unroll
  for (int i = 0; i < 4; ++i)
    WT[(size_t)(n0 + ty + 8 * i) * K + k0 + tx] = f2bf(tile[tx][ty + 8 * i]);
}

// ---------------------------------------------------------------------------
// V transpose: vb (b,t, h*64+d) bf16 -> vT (b*512 + h*64+d, t) bf16
// ---------------------------------------------------------------------------
__global__ __launch_bounds__(256) void transpose_v(
    const u16* __restrict__ vb, u16* __restrict__ vT)
{
  __shared__ u16 tile[32][33];
  int tx = threadIdx.x & 31, ty = threadIdx.x >> 5;
  int c0 = blockIdx.x * 32;     // 0..511  (h*64+d)
  int r0 = blockIdx.y * 32;     // 0..4095 (b*2048+t), tiles never cross b
  #pragma unroll
  for (int i = 0; i < 4; ++i)
    tile[ty + 8 * i][tx] = vb[(size_t)(r0 + ty + 8 * i) * NKV + c0 + tx];
  __syncthreads();
  int b = r0 >> 11, t = r0 & 2047;
  #pragma unroll
  for (int i = 0; i < 4; ++i)
    vT[((size_t)(b * NKV + c0 + ty + 8 * i)) * Ss + t + tx] = tile[tx][ty + 8 * i];
}

// ---------------------------------------------------------------------------
// m97-structure GEMM core: 128x128 tile, BK=64, global_load_lds width-16
// staging into LINEAR LDS [128][64], 2 barriers per K-step.
// ---------------------------------------------------------------------------
__device__ __forceinline__ void gemm_core128(
    const u16* __restrict__ A, const u16* __restrict__ BT, int K,
    int brow128, int bcol128, u16* __restrict__ As, u16* __restrict__ Bs,
    f32x4 (&acc)[4][4])
{
  int tid  = threadIdx.x;
  int lane = tid & 63, wave = tid >> 6;
  int wm = (wave >> 1) * 64, wn = (wave & 1) * 64;
  int m16 = lane & 15, quad = lane >> 4;
  int srow = lane >> 3;            // 0..7 within chunk
  int scol = (lane & 7) * 8;       // element col offset (16B granules)
  const u16* Ag = A  + (size_t)(brow128 + wave * 32 + srow) * K + scol;
  const u16* Bg = BT + (size_t)(bcol128 + wave * 32 + srow) * K + scol;
  u16* Asw = As + (size_t)(wave * 32) * 64;
  u16* Bsw = Bs + (size_t)(wave * 32) * 64;

  for (int k0 = 0; k0 < K; k0 += 64) {
    __syncthreads();   // all waves done reading previous tile
    #pragma unroll
    for (int i = 0; i < 4; ++i) {
      gload16(Ag + (size_t)(i * 8) * K + k0, Asw + i * 512);
      gload16(Bg + (size_t)(i * 8) * K + k0, Bsw + i * 512);
    }
    __syncthreads();   // compiler drains vmcnt(0) before barrier -> tile ready
    s16x8 af[4][2], bf[4][2];
    #pragma unroll
    for (int i = 0; i < 4; ++i) {
      af[i][0] = *(const s16x8*)&As[(size_t)(wm + i * 16 + m16) * 64 + quad * 8];
      af[i][1] = *(const s16x8*)&As[(size_t)(wm + i * 16 + m16) * 64 + 32 + quad * 8];
      bf[i][0] = *(const s16x8*)&Bs[(size_t)(wn + i * 16 + m16) * 64 + quad * 8];
      bf[i][1] = *(const s16x8*)&Bs[(size_t)(wn + i * 16 + m16) * 64 + 32 + quad * 8];
    }
    #pragma unroll
    for (int i = 0; i < 4; ++i)
      #pragma unroll
      for (int j = 0; j < 4; ++j) {
        acc[i][j] = __builtin_amdgcn_mfma_f32_16x16x32_bf16(af[i][0], bf[j][0], acc[i][j], 0, 0, 0);
        acc[i][j] = __builtin_amdgcn_mfma_f32_16x16x32_bf16(af[i][1], bf[j][1], acc[i][j], 0, 0, 0);
      }
  }
}

// Generic C = (A @ BT^T + bias) * scale, fp32 or bf16 out
template<bool BF16OUT>
__global__ __launch_bounds__(256) void gemm_bt2(
    const u16* __restrict__ A, const u16* __restrict__ BT,
    const float* __restrict__ bias, void* __restrict__ Cv,
    int N, int K, float scale)
{
  __shared__ u16 As[128 * 64];
  __shared__ u16 Bs[128 * 64];
  f32x4 acc[4][4] = {};
  gemm_core128(A, BT, K, blockIdx.y * 128, blockIdx.x * 128, As, Bs, acc);

  int lane = threadIdx.x & 63, wave = threadIdx.x >> 6;
  int wm = (wave >> 1) * 64, wn = (wave & 1) * 64;
  int m16 = lane & 15, quad = lane >> 4;
  #pragma unroll
  for (int i = 0; i < 4; ++i) {
    #pragma unroll
    for (int j = 0; j < 4; ++j) {
      int col = blockIdx.x * 128 + wn + j * 16 + m16;
      float bcol = bias[col];
      #pragma unroll
      for (int r = 0; r < 4; ++r) {
        int rowg = blockIdx.y * 128 + wm + i * 16 + quad * 4 + r;
        float val = (acc[i][j][r] + bcol) * scale;
        if constexpr (BF16OUT)
          ((u16*)Cv)[(size_t)rowg * N + col] = f2bf(val);
        else
          ((float*)Cv)[(size_t)rowg * N + col] = val;
      }
    }
  }
}

// Fused QKV projection: BT = concat rows [WqT(2048) ; WkT(512) ; WvT(512)]
__global__ __launch_bounds__(256) void gemm_qkv(
    const u16* __restrict__ A, const u16* __restrict__ BT,
    const float* __restrict__ bq, const float* __restrict__ bk,
    const float* __restrict__ bv,
    u16* __restrict__ qb, u16* __restrict__ kb, u16* __restrict__ vb)
{
  __shared__ u16 As[128 * 64];
  __shared__ u16 Bs[128 * 64];
  f32x4 acc[4][4] = {};
  gemm_core128(A, BT, Dd, blockIdx.y * 128, blockIdx.x * 128, As, Bs, acc);

  u16* outp; const float* bp; int ldo, colbase; float scale;
  if (blockIdx.x < 16)      { outp = qb; bp = bq; ldo = NQ;  colbase = blockIdx.x * 128;        scale = 0.125f * LOG2E; }
  else if (blockIdx.x < 20) { outp = kb; bp = bk; ldo = NKV; colbase = (blockIdx.x - 16) * 128; scale = 1.0f; }
  else                      { outp = vb; bp = bv; ldo = NKV; colbase = (blockIdx.x - 20) * 128; scale = 1.0f; }

  int lane = threadIdx.x & 63, wave = threadIdx.x >> 6;
  int wm = (wave >> 1) * 64, wn = (wave & 1) * 64;
  int m16 = lane & 15, quad = lane >> 4;
  #pragma unroll
  for (int i = 0; i < 4; ++i) {
    #pragma unroll
    for (int j = 0; j < 4; ++j) {
      int col = colbase + wn + j * 16 + m16;
      float bcol = bp[col];
      #pragma unroll
      for (int r = 0; r < 4; ++r) {
        int rowg = blockIdx.y * 128 + wm + i * 16 + quad * 4 + r;
        outp[(size_t)rowg * ldo + col] = f2bf((acc[i][j][r] + bcol) * scale);
      }
    }
  }
}

// ---------------------------------------------------------------------------
// Pass A: per-column softmax stats over the QUERY axis (base-2 domain).
// Qs: [64][64] linear bf16, 16B-slot XOR swizzle: LDS[r][s] = glob[r][s^(r&7)].
// Staged via global_load_lds (linear dest, inverse-swizzled source).
// ---------------------------------------------------------------------------
__global__ __launch_bounds__(256) void pass_a_mfma(
    const u16* __restrict__ qb, const u16* __restrict__ kb,
    float* __restrict__ cst)
{
  __shared__ u16 Qs[64 * 64];
  int combo = blockIdx.x;
  int qk = combo & 3, bh = combo >> 2;
  int b = bh >> 3, h = bh & 7;
  int g = blockIdx.y;                     // 0..15, longest first
  int tid = threadIdx.x;
  int lane = tid & 63, wave = tid >> 6;
  int m16 = lane & 15, quad = lane >> 4;
  int T0w = g * 128 + wave * 32;          // wave's 32 T-columns

  const u16* kbase = kb + (size_t)b * Ss * NKV + h * HD;
  const u16* qbase = qb + (size_t)b * Ss * NQ + (h * QPK + qk) * HD;

  s16x8 kf[2][2];   // B-operand frags (n=T), loaded once
  #pragma unroll
  for (int jg = 0; jg < 2; ++jg)
    #pragma unroll
    for (int dc = 0; dc < 2; ++dc)
      kf[jg][dc] = *(const s16x8*)(kbase + (size_t)(T0w + jg * 16 + m16) * NKV + dc * 32 + quad * 8);

  float ms[2] = {-1e30f, -1e30f};
  float ls[2] = {0.f, 0.f};
  // staging: wave w stages rows [8w,8w+8) and [8w+32,8w+40); src slot xor'd
  int srow  = (wave << 3) + (lane >> 3);
  int slot0 = (lane & 7) ^ (lane >> 3);
  u16* QsW = Qs + (size_t)(wave * 8) * 64;
  int sl0 = quad ^ (m16 & 7);
  int sl1 = (quad | 4) ^ (m16 & 7);
  int tDiag = T0w & ~63;

  for (int t0 = g * 128; t0 < Ss; t0 += 64) {
    __syncthreads();
    gload16(qbase + (size_t)(t0 + srow) * NQ + slot0 * 8, QsW);
    gload16(qbase + (size_t)(t0 + srow + 32) * NQ + slot0 * 8, QsW + 32 * 64);
    __syncthreads();
    if (t0 + 63 < T0w) continue;   // wave not yet active (barriers already done)

    s16x8 af[4][2];
    #pragma unroll
    for (int i = 0; i < 4; ++i) {
      af[i][0] = *(const s16x8*)&Qs[(i * 16 + m16) * 64 + sl0 * 8];
      af[i][1] = *(const s16x8*)&Qs[(i * 16 + m16) * 64 + sl1 * 8];
    }
    f32x4 acc[4][2];
    #pragma unroll
    for (int i = 0; i < 4; ++i)
      #pragma unroll
      for (int jg = 0; jg < 2; ++jg) {
        f32x4 z = {};
        z = __builtin_amdgcn_mfma_f32_16x16x32_bf16(af[i][0], kf[jg][0], z, 0, 0, 0);
        acc[i][jg] = __builtin_amdgcn_mfma_f32_16x16x32_bf16(af[i][1], kf[jg][1], z, 0, 0, 0);
      }
    if (t0 == tDiag) {   // diagonal block: mask t < T with very-low sentinel
      #pragma unroll
      for (int i = 0; i < 4; ++i)
        #pragma unroll
        for (int jg = 0; jg < 2; ++jg) {
          int tg = t0 + i * 16 + quad * 4;
          int Tg = T0w + jg * 16 + m16;
          #pragma unroll
          for (int r = 0; r < 4; ++r)
            if (tg + r < Tg) acc[i][jg][r] = -3e38f;
        }
    }
    #pragma unroll
    for (int jg = 0; jg < 2; ++jg) {
      float bm = -3e38f;
      #pragma unroll
      for (int i = 0; i < 4; ++i)
        #pragma unroll
        for (int r = 0; r < 4; ++r) bm = fmaxf(bm, acc[i][jg][r]);
      float mn = fmaxf(ms[jg], bm);
      float se = 0.f;
      #pragma unroll
      for (int i = 0; i < 4; ++i)
        #pragma unroll
        for (int r = 0; r < 4; ++r) se += exp2f(acc[i][jg][r] - mn);
      ls[jg] = ls[jg] * exp2f(ms[jg] - mn) + se;
      ms[jg] = mn;
    }
  }
  // cross-quad merge (cols live on m16; quads hold disjoint t-subsets)
  #pragma unroll
  for (int jg = 0; jg < 2; ++jg) {
    float m = ms[jg], l = ls[jg];
    #pragma unroll
    for (int off = 16; off <= 32; off <<= 1) {
      float mo = __shfl_xor(m, off);
      float lo = __shfl_xor(l, off);
      float mn = fmaxf(m, mo);
      l = l * exp2f(m - mn) + lo * exp2f(mo - mn);
      m = mn;
    }
    if (quad == 0)
      cst[(size_t)(bh * QPK + qk) * Ss + T0w + jg * 16 + m16] = m + __log2f(l);
  }
}

// ---------------------------------------------------------------------------
// Pass B: out[t,:] = sum_{T<=t} exp2(s2(t,T)-c[T]) * v[T,:]
// Ks [T][d], Vs [d][T]: [64][64] linear + 16B-slot XOR swizzle, gload_lds
// staged.  P never touches LDS: cross-quad redistribution of the score
// fragments into the PV A-operand is done with cvt_pk_bf16 + permlane swaps:
//   (R0,R2) = permlane16_swap(permlane32_swap(A0,A1))
// where A_i = cvt_pk(p[i][0],p[i][1]), B_i = cvt_pk(p[i][2],p[i][3]) and
// pa dwords = {R0, R1, R2, R3}.
// ---------------------------------------------------------------------------
__global__ __launch_bounds__(256) void pass_b_mfma(
    const u16* __restrict__ qb, const u16* __restrict__ kb,
    const u16* __restrict__ vT, const float* __restrict__ cst,
    u16* __restrict__ attn)
{
  __shared__ u16 Ks[64 * 64];
  __shared__ u16 Vs[64 * 64];
  int combo = blockIdx.x;
  int qk = combo & 3, bh = combo >> 2;
  int b = bh >> 3, h = bh & 7;
  int g = 31 - blockIdx.y;                // longest first
  int tid = threadIdx.x;
  int lane = tid & 63, wave = tid >> 6;
  int m16 = lane & 15, quad = lane >> 4;
  int trow = g * 64 + wave * 16;          // wave's 16 t-rows

  const u16* qbase = qb + (size_t)b * Ss * NQ + (h * QPK + qk) * HD;
  const u16* kbase = kb + (size_t)b * Ss * NKV + h * HD;
  const u16* vbase = vT + (size_t)(bh * 64) * Ss;
  const float* cbase = cst + (size_t)(bh * QPK + qk) * Ss;

  s16x8 qf[2];   // B-operand (n=t) frags for this wave's rows
  #pragma unroll
  for (int dc = 0; dc < 2; ++dc)
    qf[dc] = *(const s16x8*)(qbase + (size_t)(trow + m16) * NQ + dc * 32 + quad * 8);

  f32x4 oacc[4] = {};   // C-layout: row t = quad*4+r, col d = dj*16+m16
  int srow  = (wave << 3) + (lane >> 3);
  int slot0 = (lane & 7) ^ (lane >> 3);
  u16* KsW = Ks + (size_t)(wave * 8) * 64;
  u16* VsW = Vs + (size_t)(wave * 8) * 64;
  int sl0 = quad ^ (m16 & 7);
  int sl1 = (quad | 4) ^ (m16 & 7);
  int Tend = g * 64;

  for (int T0 = 0; T0 <= Tend; T0 += 64) {
    __syncthreads();
    gload16(kbase + (size_t)(T0 + srow) * NKV + slot0 * 8, KsW);
    gload16(kbase + (size_t)(T0 + srow + 32) * NKV + slot0 * 8, KsW + 32 * 64);
    gload16(vbase + (size_t)srow * Ss + T0 + slot0 * 8, VsW);
    gload16(vbase + (size_t)(srow + 32) * Ss + T0 + slot0 * 8, VsW + 32 * 64);
    __syncthreads();
    bool diag = (T0 == Tend);
    // tc = T-chunk of 32 (PV k-dim); i = score T-row-block of 16
    #pragma unroll
    for (int tc = 0; tc < 2; ++tc) {
      u32 A[2], Bw[2];
      #pragma unroll
      for (int ii = 0; ii < 2; ++ii) {
        int i = tc * 2 + ii;
        s16x8 k0 = *(const s16x8*)&Ks[(i * 16 + m16) * 64 + sl0 * 8];
        s16x8 k1 = *(const s16x8*)&Ks[(i * 16 + m16) * 64 + sl1 * 8];
        f32x4 z = {};
        z = __builtin_amdgcn_mfma_f32_16x16x32_bf16(k0, qf[0], z, 0, 0, 0);
        z = __builtin_amdgcn_mfma_f32_16x16x32_bf16(k1, qf[1], z, 0, 0, 0);
        float4 cc = *(const float4*)(cbase + T0 + i * 16 + quad * 4);
        float w0 = exp2f(z[0] - cc.x);
        float w1 = exp2f(z[1] - cc.y);
        float w2 = exp2f(z[2] - cc.z);
        float w3 = exp2f(z[3] - cc.w);
        if (diag) {
          int t  = trow + m16;
          int Tg = T0 + i * 16 + quad * 4;
          if (Tg + 0 > t) w0 = 0.f;
          if (Tg + 1 > t) w1 = 0.f;
          if (Tg + 2 > t) w2 = 0.f;
          if (Tg + 3 > t) w3 = 0.f;
        }
        A[ii]  = cvtpk_bf16(w0, w1);
        Bw[ii] = cvtpk_bf16(w2, w3);
      }
      // cross-quad redistribution: quads {0,1}->dest {0,2}, {2,3}->dest {1,3}
      asm volatile("v_permlane32_swap_b32 %0, %1" : "+v"(A[0]),  "+v"(A[1]));
      asm volatile("v_permlane16_swap_b32 %0, %1" : "+v"(A[0]),  "+v"(A[1]));
      asm volatile("v_permlane32_swap_b32 %0, %1" : "+v"(Bw[0]), "+v"(Bw[1]));
      asm volatile("v_permlane16_swap_b32 %0, %1" : "+v"(Bw[0]), "+v"(Bw[1]));
      union { uint4 u; s16x8 v; } pu;
      pu.u.x = A[0]; pu.u.y = Bw[0]; pu.u.z = A[1]; pu.u.w = Bw[1];
      s16x8 pa = pu.v;   // A-operand: P[t=m16][T = T0 + tc*32 + quad*8 + j]
      #pragma unroll
      for (int dj = 0; dj < 4; ++dj) {
        int vsl = (quad | (tc << 2)) ^ (m16 & 7);
        s16x8 vf = *(const s16x8*)&Vs[(dj * 16 + m16) * 64 + vsl * 8];
        oacc[dj] = __builtin_amdgcn_mfma_f32_16x16x32_bf16(pa, vf, oacc[dj], 0, 0, 0);
      }
    }
  }
  // ---- epilogue: attn (b, t, (h*QPK+qk)*64 + d) bf16 ----
  u16* abase = attn + (size_t)b * Ss * NQ + (h * QPK + qk) * HD;
  #pragma unroll
  for (int dj = 0; dj < 4; ++dj)
    #pragma unroll
    for (int r = 0; r < 4; ++r)
      abase[(size_t)(trow + quad * 4 + r) * NQ + dj * 16 + m16] = f2bf(oacc[dj][r]);
}

// ---------------------------------------------------------------------------
extern "C" void kernel_launch(void* const* d_in, const int* in_sizes, int n_in,
                              void* d_out, int out_size, void* d_ws, size_t ws_size,
                              hipStream_t stream)
{
  (void)in_sizes; (void)n_in; (void)out_size; (void)ws_size;
  const float* x   = (const float*)d_in[0];
  const float* lng = (const float*)d_in[1];
  const float* lnb = (const float*)d_in[2];
  const float* Wq  = (const float*)d_in[3];
  const float* bq  = (const float*)d_in[4];
  const float* Wk  = (const float*)d_in[5];
  const float* bk  = (const float*)d_in[6];
  const float* Wv  = (const float*)d_in[7];
  const float* bv  = (const float*)d_in[8];
  const float* Wo  = (const float*)d_in[9];
  const float* bo  = (const float*)d_in[10];
  float* out = (float*)d_out;

  char* ws = (char*)d_ws;
  size_t off = 0;
  auto take = [&](size_t bytes) -> char* {
    char* p = ws + off;
    off += (bytes + 255) & ~(size_t)255;
    return p;
  };
  u16*    xnb   = (u16*)take((size_t)MR * Dd * 2);             // 16 MB
  u16*    wqkvT = (u16*)take((size_t)(NQ + 2 * NKV) * Dd * 2); // 12 MB (Q;K;V rows)
  u16*    woT   = (u16*)take((size_t)Dd * NQ * 2);             // 8 MB
  u16*    qbB   = (u16*)take((size_t)MR * NQ * 2);             // 16 MB
  u16*    kbB   = (u16*)take((size_t)MR * NKV * 2);            // 4 MB
  u16*    vbB   = (u16*)take((size_t)MR * NKV * 2);            // 4 MB
  u16*    vTb   = (u16*)take((size_t)MR * NKV * 2);            // 4 MB
  float*  cst   = (float*)take((size_t)Bb * HKV * QPK * Ss * 4); // 0.5 MB
  u16*    attnb = (u16*)take((size_t)MR * NQ * 2);             // 16 MB

  ln_kernel<<<MR, 256, 0, stream>>>(x, lng, lnb, xnb);
  // concatenated BT: rows [0,2048)=WqT, [2048,2560)=WkT, [2560,3072)=WvT
  transpose_cast<<<dim3(NQ / 32, Dd / 32), 256, 0, stream>>>(Wq, wqkvT, Dd, NQ);
  transpose_cast<<<dim3(NKV / 32, Dd / 32), 256, 0, stream>>>(Wk, wqkvT + (size_t)NQ * Dd, Dd, NKV);
  transpose_cast<<<dim3(NKV / 32, Dd / 32), 256, 0, stream>>>(Wv, wqkvT + (size_t)(NQ + NKV) * Dd, Dd, NKV);
  transpose_cast<<<dim3(NQ / 32, Dd / 32), 256, 0, stream>>>(Wo, woT, Dd, NQ);

  // fused Q/K/V projection (q pre-scaled by 1/sqrt(HD) * log2(e))
  gemm_qkv<<<dim3((NQ + 2 * NKV) / 128, MR / 128), 256, 0, stream>>>(
      xnb, wqkvT, bq, bk, bv, qbB, kbB, vbB);
  transpose_v<<<dim3(NKV / 32, MR / 32), 256, 0, stream>>>(vbB, vTb);

  pass_a_mfma<<<dim3(64, 16), 256, 0, stream>>>(qbB, kbB, cst);
  pass_b_mfma<<<dim3(64, 32), 256, 0, stream>>>(qbB, kbB, vTb, cst, attnb);

  gemm_bt2<false><<<dim3(Dd / 128, MR / 128), 256, 0, stream>>>(
      attnb, woT, bo, out, Dd, NQ, 1.0f);
}

// Round 4
// 385.629 us; speedup vs baseline: 1.2817x; 1.0316x over previous
//
#include <hip/hip_runtime.h>

// Problem constants (fixed by the reference)
#define Bb  2
#define Ss  2048
#define Dd  2048
#define HKV 8
#define QPK 4
#define HD  64
#define MR  (Bb * Ss)   // 4096 token rows
#define NQ  2048        // HQ*HD
#define NKV 512         // HKV*HD

#define LOG2E 1.4426950408889634f

typedef unsigned short u16;
typedef unsigned int u32;
typedef __attribute__((ext_vector_type(8))) short s16x8;   // 8 x bf16 (4 VGPRs)
typedef __attribute__((ext_vector_type(4))) float f32x4;   // MFMA accumulator

__device__ __forceinline__ u16 f2bf(float f) {
  unsigned u = __float_as_uint(f);
  u += 0x7fffu + ((u >> 16) & 1u);   // RNE; inputs finite
  return (u16)(u >> 16);
}

// async global->LDS, 16B per lane; LDS dest is wave-uniform base + lane*16
__device__ __forceinline__ void gload16(const u16* g, u16* l) {
  __builtin_amdgcn_global_load_lds(
      (const __attribute__((address_space(1))) unsigned int*)g,
      (__attribute__((address_space(3))) unsigned int*)l, 16, 0, 0);
}

// pack two f32 -> one dword of 2 bf16 (lo = a, hi = b)
__device__ __forceinline__ u32 cvtpk_bf16(float a, float b) {
  u32 r;
  asm volatile("v_cvt_pk_bf16_f32 %0, %1, %2" : "=v"(r) : "v"(a), "v"(b));
  return r;
}

#define BAR()    asm volatile("s_barrier" ::: "memory")
#define WAITV4() asm volatile("s_waitcnt vmcnt(4)" ::: "memory")
#define WAITV0() asm volatile("s_waitcnt vmcnt(0)" ::: "memory")

// ---------------------------------------------------------------------------
// LayerNorm: one block per row, fp32 in -> bf16 out
// ---------------------------------------------------------------------------
__global__ __launch_bounds__(256) void ln_kernel(
    const float* __restrict__ x, const float* __restrict__ g,
    const float* __restrict__ be, u16* __restrict__ xn)
{
  int row = blockIdx.x;
  int tid = threadIdx.x;
  const float4* xr = (const float4*)(x + (size_t)row * Dd);
  float4 a = xr[tid];
  float4 b4 = xr[tid + 256];
  float s  = a.x + a.y + a.z + a.w + b4.x + b4.y + b4.z + b4.w;
  float ss = a.x*a.x + a.y*a.y + a.z*a.z + a.w*a.w
           + b4.x*b4.x + b4.y*b4.y + b4.z*b4.z + b4.w*b4.w;
  #pragma unroll
  for (int off = 32; off > 0; off >>= 1) {
    s  += __shfl_down(s, off);
    ss += __shfl_down(ss, off);
  }
  __shared__ float red[8];
  int lane = tid & 63, w = tid >> 6;
  if (lane == 0) { red[w] = s; red[4 + w] = ss; }
  __syncthreads();
  s  = red[0] + red[1] + red[2] + red[3];
  ss = red[4] + red[5] + red[6] + red[7];
  float mu = s * (1.0f / Dd);
  float rs = rsqrtf(ss * (1.0f / Dd) - mu * mu + 1e-5f);

  u16* xo = xn + (size_t)row * Dd;
  const float4* gv4 = (const float4*)g;
  const float4* bv4 = (const float4*)be;
  #pragma unroll
  for (int p = 0; p < 2; ++p) {
    int idx = tid + p * 256;
    float4 xv = (p == 0) ? a : b4;
    float4 gg = gv4[idx], bb = bv4[idx];
    ushort4 pk;
    pk.x = f2bf((xv.x - mu) * rs * gg.x + bb.x);
    pk.y = f2bf((xv.y - mu) * rs * gg.y + bb.y);
    pk.z = f2bf((xv.z - mu) * rs * gg.z + bb.z);
    pk.w = f2bf((xv.w - mu) * rs * gg.w + bb.w);
    *(ushort4*)(xo + idx * 4) = pk;
  }
}

// ---------------------------------------------------------------------------
// Weight transpose + cast: W (K x N) fp32 -> WT (N x K) bf16
// ---------------------------------------------------------------------------
__global__ __launch_bounds__(256) void transpose_cast(
    const float* __restrict__ W, u16* __restrict__ WT, int K, int N)
{
  __shared__ float tile[32][33];
  int tx = threadIdx.x & 31, ty = threadIdx.x >> 5;  // ty 0..7
  int n0 = blockIdx.x * 32, k0 = blockIdx.y * 32;
  #pragma unroll
  for (int i = 0; i < 4; ++i)
    tile[ty + 8 * i][tx] = W[(size_t)(k0 + ty + 8 * i) * N + n0 + tx];
  __syncthreads();
  #pragma unroll
  for (int i = 0; i < 4; ++i)
    WT[(size_t)(n0 + ty + 8 * i) * K + k0 + tx] = f2bf(tile[tx][ty + 8 * i]);
}

// ---------------------------------------------------------------------------
// V transpose: vb (b,t, h*64+d) bf16 -> vT (b*512 + h*64+d, t) bf16
// ---------------------------------------------------------------------------
__global__ __launch_bounds__(256) void transpose_v(
    const u16* __restrict__ vb, u16* __restrict__ vT)
{
  __shared__ u16 tile[32][33];
  int tx = threadIdx.x & 31, ty = threadIdx.x >> 5;
  int c0 = blockIdx.x * 32;     // 0..511  (h*64+d)
  int r0 = blockIdx.y * 32;     // 0..4095 (b*2048+t), tiles never cross b
  #pragma unroll
  for (int i = 0; i < 4; ++i)
    tile[ty + 8 * i][tx] = vb[(size_t)(r0 + ty + 8 * i) * NKV + c0 + tx];
  __syncthreads();
  int b = r0 >> 11, t = r0 & 2047;
  #pragma unroll
  for (int i = 0; i < 4; ++i)
    vT[((size_t)(b * NKV + c0 + ty + 8 * i)) * Ss + t + tx] = tile[tx][ty + 8 * i];
}

// ---------------------------------------------------------------------------
// 256x256 8-phase GEMM core (T2+T3+T4+T5).  512 threads = 8 waves (2M x 4N).
// BK=64, double-buffered LDS 128 KiB, 16B-slot XOR swizzle (slot ^= row&7).
// Per K-tile: 4 phases x {ds_read subtile || stage 1 half-tile -> barrier ->
// setprio(1) 16 MFMA setprio(0) -> barrier}.  Stage order per tile t:
// {A.h0(t+1), A.h1(t+1), B.h0(t+2), B.h1(t+2)} so boundary vmcnt(4) leaves
// exactly B(t+2) in flight and forces A(t+1)+B(t+1) complete.
// acc[8][4]: row = wr*128+mi*16+quad*4+rr, col = (wc>>1)*128+(wc&1)*64+nj*16+m16.
// ---------------------------------------------------------------------------
__device__ __forceinline__ void gemm8_core(
    const u16* __restrict__ A, const u16* __restrict__ BT, int K,
    int brow, int bcol, u16* __restrict__ As, u16* __restrict__ Bs,
    f32x4 (&acc)[8][4])
{
  const int tid  = threadIdx.x;
  const int lane = tid & 63;
  const int wave = tid >> 6;
  const int wr = wave >> 2, wc = wave & 3;
  const int m16 = lane & 15, quad = lane >> 4;
  const int NT = K >> 6;

  // staging: per half-tile (128 rows x 64 k), 2 sweeps of 512 lanes x 16B.
  // linear LDS dest + inverse-swizzled global source (rule #21).
  const int r0 = tid >> 3;                  // row within half, sweep 0
  const int sg = (tid & 7) ^ (r0 & 7);      // source 16B-slot (r0&7 == (r0+64)&7)
  const u16* Asrc = A  + (size_t)(brow + r0) * K + sg * 8;
  const u16* Bsrc = BT + (size_t)(bcol + r0) * K + sg * 8;
  u16* AsW = As + wave * 512;               // + bi*16384 + h*8192 (+4096 sweep1)
  u16* BsW = Bs + wave * 512;
  const size_t a64 = (size_t)64 * K;

  // fragment-read slots (swizzled): row&7 == m16&7 for all frags
  const int sl0 = (quad ^ (m16 & 7)) * 8;        // kh=0
  const int sl1 = ((quad | 4) ^ (m16 & 7)) * 8;  // kh=1
  const u16* Afr = As + wr * 8192 + m16 * 64;
  const u16* Bfr = Bs + (wc >> 1) * 8192 + ((wc & 1) * 64 + m16) * 64;

  // ---- prologue: A(0).h01, B(0).h01, then B(1).h01 ----
  #pragma unroll
  for (int h = 0; h < 2; ++h) {
    gload16(Asrc + (size_t)(h * 128) * K, AsW + h * 8192);
    gload16(Asrc + (size_t)(h * 128) * K + a64, AsW + h * 8192 + 4096);
    gload16(Bsrc + (size_t)(h * 128) * K, BsW + h * 8192);
    gload16(Bsrc + (size_t)(h * 128) * K + a64, BsW + h * 8192 + 4096);
  }
  #pragma unroll
  for (int h = 0; h < 2; ++h) {
    gload16(Bsrc + (size_t)(h * 128) * K + 64, BsW + 16384 + h * 8192);
    gload16(Bsrc + (size_t)(h * 128) * K + a64 + 64, BsW + 16384 + h * 8192 + 4096);
  }
  WAITV4();
  BAR();

  for (int t = 0; t < NT; ++t) {
    const int bi = t & 1;
    const u16* Abuf = Afr + bi * 16384;
    const u16* Bbuf = Bfr + bi * 16384;
    s16x8 bfr[4][2];
    #pragma unroll
    for (int ph = 0; ph < 4; ++ph) {
      // ds-load this phase's A fragments (mi = 2ph, 2ph+1)
      s16x8 a0k0 = *(const s16x8*)(Abuf + (ph * 2 + 0) * 1024 + sl0);
      s16x8 a0k1 = *(const s16x8*)(Abuf + (ph * 2 + 0) * 1024 + sl1);
      s16x8 a1k0 = *(const s16x8*)(Abuf + (ph * 2 + 1) * 1024 + sl0);
      s16x8 a1k1 = *(const s16x8*)(Abuf + (ph * 2 + 1) * 1024 + sl1);
      if (ph == 0) {   // all B fragments for this K-tile (frees B region at ph2)
        #pragma unroll
        for (int nj = 0; nj < 4; ++nj) {
          bfr[nj][0] = *(const s16x8*)(Bbuf + nj * 1024 + sl0);
          bfr[nj][1] = *(const s16x8*)(Bbuf + nj * 1024 + sl1);
        }
      }
      // stage issue (one half-tile per phase)
      if (ph < 2) {
        if (t + 1 < NT) {
          const u16* g = Asrc + (size_t)(ph * 128) * K + (t + 1) * 64;
          u16* l = AsW + (bi ^ 1) * 16384 + ph * 8192;
          gload16(g, l);
          gload16(g + a64, l + 4096);
        }
      } else {
        if (t + 2 < NT) {
          const u16* g = Bsrc + (size_t)((ph - 2) * 128) * K + (t + 2) * 64;
          u16* l = BsW + bi * 16384 + (ph - 2) * 8192;
          gload16(g, l);
          gload16(g + a64, l + 4096);
        }
      }
      BAR();
      __builtin_amdgcn_s_setprio(1);
      #pragma unroll
      for (int nj = 0; nj < 4; ++nj) {
        acc[ph*2+0][nj] = __builtin_amdgcn_mfma_f32_16x16x32_bf16(a0k0, bfr[nj][0], acc[ph*2+0][nj], 0, 0, 0);
        acc[ph*2+0][nj] = __builtin_amdgcn_mfma_f32_16x16x32_bf16(a0k1, bfr[nj][1], acc[ph*2+0][nj], 0, 0, 0);
        acc[ph*2+1][nj] = __builtin_amdgcn_mfma_f32_16x16x32_bf16(a1k0, bfr[nj][0], acc[ph*2+1][nj], 0, 0, 0);
        acc[ph*2+1][nj] = __builtin_amdgcn_mfma_f32_16x16x32_bf16(a1k1, bfr[nj][1], acc[ph*2+1][nj], 0, 0, 0);
      }
      __builtin_amdgcn_s_setprio(0);
      if (ph == 3) {
        if (t + 2 < NT) WAITV4(); else WAITV0();
      }
      BAR();
    }
  }
}

// Wo projection: C(M,N) fp32 = A(M,K) @ BT(N,K)^T + bias
__global__ __launch_bounds__(512) void gemm8_bt(
    const u16* __restrict__ A, const u16* __restrict__ BT,
    const float* __restrict__ bias, float* __restrict__ C, int N, int K)
{
  __shared__ u16 As[32768];
  __shared__ u16 Bs[32768];
  int nbx = N >> 8;
  int id  = blockIdx.y * nbx + blockIdx.x;
  int nwg = gridDim.x * gridDim.y;         // multiple of 8 by construction
  int swz = (id & 7) * (nwg >> 3) + (id >> 3);
  int bx = swz % nbx, by = swz / nbx;

  f32x4 acc[8][4] = {};
  gemm8_core(A, BT, K, by * 256, bx * 256, As, Bs, acc);

  int lane = threadIdx.x & 63, wave = threadIdx.x >> 6;
  int wr = wave >> 2, wc = wave & 3;
  int m16 = lane & 15, quad = lane >> 4;
  int colb = bx * 256 + (wc >> 1) * 128 + (wc & 1) * 64;
  #pragma unroll
  for (int nj = 0; nj < 4; ++nj) {
    int col = colb + nj * 16 + m16;
    float bc = bias[col];
    #pragma unroll
    for (int mi = 0; mi < 8; ++mi)
      #pragma unroll
      for (int rr = 0; rr < 4; ++rr) {
        int row = by * 256 + wr * 128 + mi * 16 + quad * 4 + rr;
        C[(size_t)row * N + col] = acc[mi][nj][rr] + bc;
      }
  }
}

// Fused QKV projection: BT = concat rows [WqT(2048) ; WkT(512) ; WvT(512)]
__global__ __launch_bounds__(512) void gemm8_qkv(
    const u16* __restrict__ A, const u16* __restrict__ BT,
    const float* __restrict__ bq, const float* __restrict__ bk,
    const float* __restrict__ bv,
    u16* __restrict__ qb, u16* __restrict__ kb, u16* __restrict__ vb)
{
  __shared__ u16 As[32768];
  __shared__ u16 Bs[32768];
  int nbx = 12;
  int id  = blockIdx.y * nbx + blockIdx.x;
  int nwg = 192;
  int swz = (id & 7) * (nwg >> 3) + (id >> 3);
  int bx = swz % nbx, by = swz / nbx;

  f32x4 acc[8][4] = {};
  gemm8_core(A, BT, Dd, by * 256, bx * 256, As, Bs, acc);

  u16* outp; const float* bp; int ldo, cb; float scale;
  if (bx < 8)       { outp = qb; bp = bq; ldo = NQ;  cb = bx * 256;        scale = 0.125f * LOG2E; }
  else if (bx < 10) { outp = kb; bp = bk; ldo = NKV; cb = (bx - 8) * 256;  scale = 1.0f; }
  else              { outp = vb; bp = bv; ldo = NKV; cb = (bx - 10) * 256; scale = 1.0f; }

  int lane = threadIdx.x & 63, wave = threadIdx.x >> 6;
  int wr = wave >> 2, wc = wave & 3;
  int m16 = lane & 15, quad = lane >> 4;
  int colb = cb + (wc >> 1) * 128 + (wc & 1) * 64;
  #pragma unroll
  for (int nj = 0; nj < 4; ++nj) {
    int col = colb + nj * 16 + m16;
    float bc = bp[col];
    #pragma unroll
    for (int mi = 0; mi < 8; ++mi)
      #pragma unroll
      for (int rr = 0; rr < 4; ++rr) {
        int row = by * 256 + wr * 128 + mi * 16 + quad * 4 + rr;
        outp[(size_t)row * ldo + col] = f2bf((acc[mi][nj][rr] + bc) * scale);
      }
  }
}

// ---------------------------------------------------------------------------
// Pass A: per-column softmax stats over the QUERY axis (base-2 domain).
// Qs: [64][64] linear bf16, 16B-slot XOR swizzle: LDS[r][s] = glob[r][s^(r&7)].
// Staged via global_load_lds (linear dest, inverse-swizzled source).
// ---------------------------------------------------------------------------
__global__ __launch_bounds__(256) void pass_a_mfma(
    const u16* __restrict__ qb, const u16* __restrict__ kb,
    float* __restrict__ cst)
{
  __shared__ u16 Qs[64 * 64];
  int combo = blockIdx.x;
  int qk = combo & 3, bh = combo >> 2;
  int b = bh >> 3, h = bh & 7;
  int g = blockIdx.y;                     // 0..15, longest first
  int tid = threadIdx.x;
  int lane = tid & 63, wave = tid >> 6;
  int m16 = lane & 15, quad = lane >> 4;
  int T0w = g * 128 + wave * 32;          // wave's 32 T-columns

  const u16* kbase = kb + (size_t)b * Ss * NKV + h * HD;
  const u16* qbase = qb + (size_t)b * Ss * NQ + (h * QPK + qk) * HD;

  s16x8 kf[2][2];   // B-operand frags (n=T), loaded once
  #pragma unroll
  for (int jg = 0; jg < 2; ++jg)
    #pragma unroll
    for (int dc = 0; dc < 2; ++dc)
      kf[jg][dc] = *(const s16x8*)(kbase + (size_t)(T0w + jg * 16 + m16) * NKV + dc * 32 + quad * 8);

  float ms[2] = {-1e30f, -1e30f};
  float ls[2] = {0.f, 0.f};
  // staging: wave w stages rows [8w,8w+8) and [8w+32,8w+40); src slot xor'd
  int srow  = (wave << 3) + (lane >> 3);
  int slot0 = (lane & 7) ^ (lane >> 3);
  u16* QsW = Qs + (size_t)(wave * 8) * 64;
  int sl0 = quad ^ (m16 & 7);
  int sl1 = (quad | 4) ^ (m16 & 7);
  int tDiag = T0w & ~63;

  for (int t0 = g * 128; t0 < Ss; t0 += 64) {
    __syncthreads();
    gload16(qbase + (size_t)(t0 + srow) * NQ + slot0 * 8, QsW);
    gload16(qbase + (size_t)(t0 + srow + 32) * NQ + slot0 * 8, QsW + 32 * 64);
    __syncthreads();
    if (t0 + 63 < T0w) continue;   // wave not yet active (barriers already done)

    s16x8 af[4][2];
    #pragma unroll
    for (int i = 0; i < 4; ++i) {
      af[i][0] = *(const s16x8*)&Qs[(i * 16 + m16) * 64 + sl0 * 8];
      af[i][1] = *(const s16x8*)&Qs[(i * 16 + m16) * 64 + sl1 * 8];
    }
    f32x4 acc[4][2];
    #pragma unroll
    for (int i = 0; i < 4; ++i)
      #pragma unroll
      for (int jg = 0; jg < 2; ++jg) {
        f32x4 z = {};
        z = __builtin_amdgcn_mfma_f32_16x16x32_bf16(af[i][0], kf[jg][0], z, 0, 0, 0);
        acc[i][jg] = __builtin_amdgcn_mfma_f32_16x16x32_bf16(af[i][1], kf[jg][1], z, 0, 0, 0);
      }
    if (t0 == tDiag) {   // diagonal block: mask t < T with very-low sentinel
      #pragma unroll
      for (int i = 0; i < 4; ++i)
        #pragma unroll
        for (int jg = 0; jg < 2; ++jg) {
          int tg = t0 + i * 16 + quad * 4;
          int Tg = T0w + jg * 16 + m16;
          #pragma unroll
          for (int r = 0; r < 4; ++r)
            if (tg + r < Tg) acc[i][jg][r] = -3e38f;
        }
    }
    #pragma unroll
    for (int jg = 0; jg < 2; ++jg) {
      float bm = -3e38f;
      #pragma unroll
      for (int i = 0; i < 4; ++i)
        #pragma unroll
        for (int r = 0; r < 4; ++r) bm = fmaxf(bm, acc[i][jg][r]);
      float mn = fmaxf(ms[jg], bm);
      float se = 0.f;
      #pragma unroll
      for (int i = 0; i < 4; ++i)
        #pragma unroll
        for (int r = 0; r < 4; ++r) se += exp2f(acc[i][jg][r] - mn);
      ls[jg] = ls[jg] * exp2f(ms[jg] - mn) + se;
      ms[jg] = mn;
    }
  }
  // cross-quad merge (cols live on m16; quads hold disjoint t-subsets)
  #pragma unroll
  for (int jg = 0; jg < 2; ++jg) {
    float m = ms[jg], l = ls[jg];
    #pragma unroll
    for (int off = 16; off <= 32; off <<= 1) {
      float mo = __shfl_xor(m, off);
      float lo = __shfl_xor(l, off);
      float mn = fmaxf(m, mo);
      l = l * exp2f(m - mn) + lo * exp2f(mo - mn);
      m = mn;
    }
    if (quad == 0)
      cst[(size_t)(bh * QPK + qk) * Ss + T0w + jg * 16 + m16] = m + __log2f(l);
  }
}

// ---------------------------------------------------------------------------
// Pass B: out[t,:] = sum_{T<=t} exp2(s2(t,T)-c[T]) * v[T,:]
// Ks [T][d], Vs [d][T]: [64][64] linear + 16B-slot XOR swizzle, gload_lds
// staged.  P never touches LDS: cross-quad redistribution via cvt_pk_bf16 +
// permlane32/16 swaps.
// ---------------------------------------------------------------------------
__global__ __launch_bounds__(256) void pass_b_mfma(
    const u16* __restrict__ qb, const u16* __restrict__ kb,
    const u16* __restrict__ vT, const float* __restrict__ cst,
    u16* __restrict__ attn)
{
  __shared__ u16 Ks[64 * 64];
  __shared__ u16 Vs[64 * 64];
  int combo = blockIdx.x;
  int qk = combo & 3, bh = combo >> 2;
  int b = bh >> 3, h = bh & 7;
  int g = 31 - blockIdx.y;                // longest first
  int tid = threadIdx.x;
  int lane = tid & 63, wave = tid >> 6;
  int m16 = lane & 15, quad = lane >> 4;
  int trow = g * 64 + wave * 16;          // wave's 16 t-rows

  const u16* qbase = qb + (size_t)b * Ss * NQ + (h * QPK + qk) * HD;
  const u16* kbase = kb + (size_t)b * Ss * NKV + h * HD;
  const u16* vbase = vT + (size_t)(bh * 64) * Ss;
  const float* cbase = cst + (size_t)(bh * QPK + qk) * Ss;

  s16x8 qf[2];   // B-operand (n=t) frags for this wave's rows
  #pragma unroll
  for (int dc = 0; dc < 2; ++dc)
    qf[dc] = *(const s16x8*)(qbase + (size_t)(trow + m16) * NQ + dc * 32 + quad * 8);

  f32x4 oacc[4] = {};   // C-layout: row t = quad*4+r, col d = dj*16+m16
  int srow  = (wave << 3) + (lane >> 3);
  int slot0 = (lane & 7) ^ (lane >> 3);
  u16* KsW = Ks + (size_t)(wave * 8) * 64;
  u16* VsW = Vs + (size_t)(wave * 8) * 64;
  int sl0 = quad ^ (m16 & 7);
  int sl1 = (quad | 4) ^ (m16 & 7);
  int Tend = g * 64;

  for (int T0 = 0; T0 <= Tend; T0 += 64) {
    __syncthreads();
    gload16(kbase + (size_t)(T0 + srow) * NKV + slot0 * 8, KsW);
    gload16(kbase + (size_t)(T0 + srow + 32) * NKV + slot0 * 8, KsW + 32 * 64);
    gload16(vbase + (size_t)srow * Ss + T0 + slot0 * 8, VsW);
    gload16(vbase + (size_t)(srow + 32) * Ss + T0 + slot0 * 8, VsW + 32 * 64);
    __syncthreads();
    bool diag = (T0 == Tend);
    // tc = T-chunk of 32 (PV k-dim); i = score T-row-block of 16
    #pragma unroll
    for (int tc = 0; tc < 2; ++tc) {
      u32 A[2], Bw[2];
      #pragma unroll
      for (int ii = 0; ii < 2; ++ii) {
        int i = tc * 2 + ii;
        s16x8 k0 = *(const s16x8*)&Ks[(i * 16 + m16) * 64 + sl0 * 8];
        s16x8 k1 = *(const s16x8*)&Ks[(i * 16 + m16) * 64 + sl1 * 8];
        f32x4 z = {};
        z = __builtin_amdgcn_mfma_f32_16x16x32_bf16(k0, qf[0], z, 0, 0, 0);
        z = __builtin_amdgcn_mfma_f32_16x16x32_bf16(k1, qf[1], z, 0, 0, 0);
        float4 cc = *(const float4*)(cbase + T0 + i * 16 + quad * 4);
        float w0 = exp2f(z[0] - cc.x);
        float w1 = exp2f(z[1] - cc.y);
        float w2 = exp2f(z[2] - cc.z);
        float w3 = exp2f(z[3] - cc.w);
        if (diag) {
          int t  = trow + m16;
          int Tg = T0 + i * 16 + quad * 4;
          if (Tg + 0 > t) w0 = 0.f;
          if (Tg + 1 > t) w1 = 0.f;
          if (Tg + 2 > t) w2 = 0.f;
          if (Tg + 3 > t) w3 = 0.f;
        }
        A[ii]  = cvtpk_bf16(w0, w1);
        Bw[ii] = cvtpk_bf16(w2, w3);
      }
      // cross-quad redistribution: quads {0,1}->dest {0,2}, {2,3}->dest {1,3}
      asm volatile("v_permlane32_swap_b32 %0, %1" : "+v"(A[0]),  "+v"(A[1]));
      asm volatile("v_permlane16_swap_b32 %0, %1" : "+v"(A[0]),  "+v"(A[1]));
      asm volatile("v_permlane32_swap_b32 %0, %1" : "+v"(Bw[0]), "+v"(Bw[1]));
      asm volatile("v_permlane16_swap_b32 %0, %1" : "+v"(Bw[0]), "+v"(Bw[1]));
      union { uint4 u; s16x8 v; } pu;
      pu.u.x = A[0]; pu.u.y = Bw[0]; pu.u.z = A[1]; pu.u.w = Bw[1];
      s16x8 pa = pu.v;   // A-operand: P[t=m16][T = T0 + tc*32 + quad*8 + j]
      #pragma unroll
      for (int dj = 0; dj < 4; ++dj) {
        int vsl = (quad | (tc << 2)) ^ (m16 & 7);
        s16x8 vf = *(const s16x8*)&Vs[(dj * 16 + m16) * 64 + vsl * 8];
        oacc[dj] = __builtin_amdgcn_mfma_f32_16x16x32_bf16(pa, vf, oacc[dj], 0, 0, 0);
      }
    }
  }
  // ---- epilogue: attn (b, t, (h*QPK+qk)*64 + d) bf16 ----
  u16* abase = attn + (size_t)b * Ss * NQ + (h * QPK + qk) * HD;
  #pragma unroll
  for (int dj = 0; dj < 4; ++dj)
    #pragma unroll
    for (int r = 0; r < 4; ++r)
      abase[(size_t)(trow + quad * 4 + r) * NQ + dj * 16 + m16] = f2bf(oacc[dj][r]);
}

// ---------------------------------------------------------------------------
extern "C" void kernel_launch(void* const* d_in, const int* in_sizes, int n_in,
                              void* d_out, int out_size, void* d_ws, size_t ws_size,
                              hipStream_t stream)
{
  (void)in_sizes; (void)n_in; (void)out_size; (void)ws_size;
  const float* x   = (const float*)d_in[0];
  const float* lng = (const float*)d_in[1];
  const float* lnb = (const float*)d_in[2];
  const float* Wq  = (const float*)d_in[3];
  const float* bq  = (const float*)d_in[4];
  const float* Wk  = (const float*)d_in[5];
  const float* bk  = (const float*)d_in[6];
  const float* Wv  = (const float*)d_in[7];
  const float* bv  = (const float*)d_in[8];
  const float* Wo  = (const float*)d_in[9];
  const float* bo  = (const float*)d_in[10];
  float* out = (float*)d_out;

  char* ws = (char*)d_ws;
  size_t off = 0;
  auto take = [&](size_t bytes) -> char* {
    char* p = ws + off;
    off += (bytes + 255) & ~(size_t)255;
    return p;
  };
  u16*    xnb   = (u16*)take((size_t)MR * Dd * 2);             // 16 MB
  u16*    wqkvT = (u16*)take((size_t)(NQ + 2 * NKV) * Dd * 2); // 12 MB (Q;K;V rows)
  u16*    woT   = (u16*)take((size_t)Dd * NQ * 2);             // 8 MB
  u16*    qbB   = (u16*)take((size_t)MR * NQ * 2);             // 16 MB
  u16*    kbB   = (u16*)take((size_t)MR * NKV * 2);            // 4 MB
  u16*    vbB   = (u16*)take((size_t)MR * NKV * 2);            // 4 MB
  u16*    vTb   = (u16*)take((size_t)MR * NKV * 2);            // 4 MB
  float*  cst   = (float*)take((size_t)Bb * HKV * QPK * Ss * 4); // 0.5 MB
  u16*    attnb = (u16*)take((size_t)MR * NQ * 2);             // 16 MB

  ln_kernel<<<MR, 256, 0, stream>>>(x, lng, lnb, xnb);
  // concatenated BT: rows [0,2048)=WqT, [2048,2560)=WkT, [2560,3072)=WvT
  transpose_cast<<<dim3(NQ / 32, Dd / 32), 256, 0, stream>>>(Wq, wqkvT, Dd, NQ);
  transpose_cast<<<dim3(NKV / 32, Dd / 32), 256, 0, stream>>>(Wk, wqkvT + (size_t)NQ * Dd, Dd, NKV);
  transpose_cast<<<dim3(NKV / 32, Dd / 32), 256, 0, stream>>>(Wv, wqkvT + (size_t)(NQ + NKV) * Dd, Dd, NKV);
  transpose_cast<<<dim3(NQ / 32, Dd / 32), 256, 0, stream>>>(Wo, woT, Dd, NQ);

  // fused Q/K/V projection (q pre-scaled by 1/sqrt(HD) * log2(e))
  gemm8_qkv<<<dim3(12, 16), 512, 0, stream>>>(xnb, wqkvT, bq, bk, bv, qbB, kbB, vbB);
  transpose_v<<<dim3(NKV / 32, MR / 32), 256, 0, stream>>>(vbB, vTb);

  pass_a_mfma<<<dim3(64, 16), 256, 0, stream>>>(qbB, kbB, cst);
  pass_b_mfma<<<dim3(64, 32), 256, 0, stream>>>(qbB, kbB, vTb, cst, attnb);

  gemm8_bt<<<dim3(8, 16), 512, 0, stream>>>(attnb, woT, bo, out, Dd, NQ);
}